// Round 4
// baseline (268.267 us; speedup 1.0000x reference)
//
#include <hip/hip_runtime.h>
#include <math.h>

// Problem dims
#define BB 8
#define SS 32
#define NN 512
#define FIN 24
#define CC 56
#define EBN 262144
#define ESN 8192
#define EDD 4
#define NG (SS*NN)   // 16384 nodes per sample in bend graph
#define BCAP 128     // bucket capacity (avg deg 16, Poisson-tail max ~45)
#define SCAP 128

// ---------------- small helpers ----------------
__device__ __forceinline__ float bf2f(unsigned short u) {
    union { unsigned int i; float f; } w; w.i = ((unsigned int)u) << 16; return w.f;
}
__device__ __forceinline__ unsigned short f2bf(float f) {
    union { float f; unsigned int i; } w; w.f = f;
    unsigned int r = (w.i + 0x7FFFu + ((w.i >> 16) & 1u)) >> 16;
    return (unsigned short)r;
}
__device__ __forceinline__ float wave_sum(float v) {
    #pragma unroll
    for (int o = 32; o > 0; o >>= 1) v += __shfl_xor(v, o);
    return v;
}

// ---------------- K0: prep params + zero bucket counts ----------------
// P layout: [0..3]=u_bend, [4]=c_bend, [5..8]=u_sec, [9]=c_sec, [10]=w0, [11]=w1
//           [16..39]=wa_src_b, [40..63]=wa_dst_b, [64..87]=wa_src_s, [88..111]=wa_dst_s
__global__ void k0_init(const float* enc_W, const float* enc_b,
                        const float* Wb, const float* a_src_b, const float* a_dst_b,
                        const float* We_b, const float* a_e_b,
                        const float* Ws, const float* a_src_s, const float* a_dst_s,
                        const float* We_s, const float* a_e_s,
                        const float* mix_w, float* P,
                        int* bcnt, int* scnt) {
    int i = blockIdx.x * blockDim.x + threadIdx.x;
    if (i < NG) bcnt[i] = 0;
    if (i < NN) scnt[i] = 0;
    if (i < 96) {
        // fold W @ a vectors: P[16 + v*24 + f] = sum_c W[f][c] * a[c]
        int v = i / FIN, f = i % FIN;
        const float* W = (v < 2) ? Wb : Ws;
        const float* a = (v == 0) ? a_src_b : (v == 1) ? a_dst_b : (v == 2) ? a_src_s : a_dst_s;
        float d = 0.f;
        for (int c = 0; c < CC; ++c) d = fmaf(W[f*CC + c], a[c], d);
        P[16 + i] = d;
    }
    if (i == 0) {
        float tb[EDD], ts[EDD];
        for (int j = 0; j < EDD; ++j) {
            float vb = 0.f, vs = 0.f;
            for (int c = 0; c < CC; ++c) {
                vb += We_b[j*CC + c] * a_e_b[c];
                vs += We_s[j*CC + c] * a_e_s[c];
            }
            tb[j] = vb; ts[j] = vs;
        }
        float cb = 0.f, cs = 0.f;
        for (int j = 0; j < EDD; ++j) { cb += enc_b[j]*tb[j]; cs += enc_b[j]*ts[j]; }
        for (int d = 0; d < EDD; ++d) {
            float ub = 0.f, us = 0.f;
            for (int j = 0; j < EDD; ++j) {
                ub += enc_W[d*EDD + j] * tb[j];
                us += enc_W[d*EDD + j] * ts[j];
            }
            P[d] = ub; P[5 + d] = us;
        }
        P[4] = cb; P[9] = cs;
        float m0 = mix_w[0], m1 = mix_w[1];
        float mm = fmaxf(m0, m1);
        float e0 = expf(m0 - mm), e1 = expf(m1 - mm);
        float inv = 1.f / (e0 + e1);
        P[10] = e0 * inv; P[11] = e1 * inv;
    }
}

// ---------------- K1: bucket fill + node features + edge logits (grid-partitioned)
#define FEAT_NB (BB*NG/4)              // 32768 blocks, 4 waves each
#define FILLB_NB ((EBN+255)/256)       // 1024
#define FILLS_NB ((ESN+255)/256)       // 32
#define ELOG_NB ((BB*(EBN+ESN)+255)/256) // 8448

__global__ __launch_bounds__(256) void k1_build(
        const float* __restrict__ x,
        const int* __restrict__ bend_ei, const int* __restrict__ sec_ei,
        const float* __restrict__ bend_attr, const float* __restrict__ sec_attr,
        const float* __restrict__ Wb, const float* __restrict__ Ws,
        const float* __restrict__ P,
        unsigned short* __restrict__ h_b, unsigned short* __restrict__ h_s,
        float* __restrict__ asb, float* __restrict__ adb,
        float* __restrict__ ass, float* __restrict__ ads,
        float* __restrict__ elog_b, float* __restrict__ elog_s,
        int* __restrict__ bcnt, int2* __restrict__ bbuck,
        int* __restrict__ scnt, int2* __restrict__ sbuck) {
    int blk = blockIdx.x;
    if (blk < FEAT_NB) {
        // ---- node features: h = x@W (bf16 store); alphas via folded W@a vectors
        int wave = (blk << 2) + (threadIdx.x >> 6);
        int lane = threadIdx.x & 63;
        size_t ng = (size_t)wave;
        const float4* x4 = (const float4*)(x + ng * FIN);
        float xv[FIN];
        #pragma unroll
        for (int q = 0; q < FIN/4; ++q) {
            float4 v = x4[q];
            xv[4*q+0] = v.x; xv[4*q+1] = v.y; xv[4*q+2] = v.z; xv[4*q+3] = v.w;
        }
        if (lane < CC) {
            float hb = 0.f, hs = 0.f;
            #pragma unroll
            for (int f = 0; f < FIN; ++f) {
                hb = fmaf(xv[f], Wb[f*CC + lane], hb);
                hs = fmaf(xv[f], Ws[f*CC + lane], hs);
            }
            h_b[ng*CC + lane] = f2bf(hb);
            h_s[ng*CC + lane] = f2bf(hs);
        } else if (lane < 60) {
            const float* wa = P + 16 + (lane - 56) * FIN;
            float d = 0.f;
            #pragma unroll
            for (int f = 0; f < FIN; ++f) d = fmaf(xv[f], wa[f], d);
            float* dst = (lane == 56) ? asb : (lane == 57) ? adb : (lane == 58) ? ass : ads;
            dst[ng] = d;
        }
    } else if (blk < FEAT_NB + FILLB_NB) {
        // ---- bend bucket fill
        int i = (blk - FEAT_NB) * 256 + threadIdx.x;
        if (i < EBN) {
            int d = bend_ei[EBN + i];
            int p = atomicAdd(&bcnt[d], 1);
            if (p < BCAP) bbuck[(size_t)d * BCAP + p] = make_int2(bend_ei[i], i);
        }
    } else if (blk < FEAT_NB + FILLB_NB + FILLS_NB) {
        // ---- section bucket fill
        int i = (blk - FEAT_NB - FILLB_NB) * 256 + threadIdx.x;
        if (i < ESN) {
            int d = sec_ei[ESN + i];
            int p = atomicAdd(&scnt[d], 1);
            if (p < SCAP) sbuck[(size_t)d * SCAP + p] = make_int2(sec_ei[i], i);
        }
    } else {
        // ---- per-edge scalar logit terms
        int i = (blk - FEAT_NB - FILLB_NB - FILLS_NB) * 256 + threadIdx.x;
        const int nb = BB * EBN;
        if (i < nb) {
            float4 a = ((const float4*)bend_attr)[i];
            elog_b[i] = a.x*P[0] + a.y*P[1] + a.z*P[2] + a.w*P[3] + P[4];
        } else if (i < nb + BB * ESN) {
            int j = i - nb;
            float4 a = ((const float4*)sec_attr)[j];
            elog_s[j] = a.x*P[5] + a.y*P[6] + a.z*P[7] + a.w*P[8] + P[9];
        }
    }
}

// ---------------- accumulation over LDS-packed (p, src) pairs ----------------
// lreg holds pairs: float4 = {p0, src0_bits, p1, src1_bits}; same-address LDS
// reads across the wave broadcast (no bank conflicts).
__device__ __forceinline__ float accum_pairs(const float4* __restrict__ lreg, int deg,
                                             const unsigned short* __restrict__ h, int cl) {
    float acc = 0.f;
    int degQ = (deg + 1) >> 1;
    int j = 0;
    for (; j + 4 <= degQ; j += 4) {     // 8 edges per iter
        float4 q0 = lreg[j], q1 = lreg[j+1], q2 = lreg[j+2], q3 = lreg[j+3];
        float v0 = bf2f(h[__float_as_int(q0.y)*CC + cl]);
        float v1 = bf2f(h[__float_as_int(q0.w)*CC + cl]);
        float v2 = bf2f(h[__float_as_int(q1.y)*CC + cl]);
        float v3 = bf2f(h[__float_as_int(q1.w)*CC + cl]);
        float v4 = bf2f(h[__float_as_int(q2.y)*CC + cl]);
        float v5 = bf2f(h[__float_as_int(q2.w)*CC + cl]);
        float v6 = bf2f(h[__float_as_int(q3.y)*CC + cl]);
        float v7 = bf2f(h[__float_as_int(q3.w)*CC + cl]);
        acc = fmaf(q0.x, v0, acc); acc = fmaf(q0.z, v1, acc);
        acc = fmaf(q1.x, v2, acc); acc = fmaf(q1.z, v3, acc);
        acc = fmaf(q2.x, v4, acc); acc = fmaf(q2.z, v5, acc);
        acc = fmaf(q3.x, v6, acc); acc = fmaf(q3.z, v7, acc);
    }
    for (; j < degQ; ++j) {
        float4 q = lreg[j];
        acc = fmaf(q.x, bf2f(h[__float_as_int(q.y)*CC + cl]), acc);
        acc = fmaf(q.z, bf2f(h[__float_as_int(q.w)*CC + cl]), acc);
    }
    return acc;
}

// rare fallback: degree > 64 (chunked, no-max softmax)
__device__ __noinline__ float gat_big(const int2* __restrict__ buck, int deg,
                                      const float* __restrict__ asrc,
                                      const float* __restrict__ el,
                                      const unsigned short* __restrict__ h,
                                      float adg, int lane, int cl, float4* lreg) {
    if (deg <= 0) return 0.f;
    float2* wp = (float2*)lreg;
    float acc = 0.f, sum = 0.f;
    for (int k0 = 0; k0 < deg; k0 += 64) {
        int k = k0 + lane;
        bool v = k < deg;
        int2 se = buck[v ? k : 0];
        float lg = asrc[se.x] + adg + el[se.y];
        lg = lg >= 0.f ? lg : 0.2f * lg;
        float p = v ? __expf(lg) : 0.f;
        asm volatile("s_waitcnt lgkmcnt(0)" ::: "memory");  // prior reads done before overwrite
        wp[lane] = make_float2(p, __int_as_float(se.x));
        sum += wave_sum(p);
        asm volatile("s_waitcnt lgkmcnt(0)" ::: "memory");
        int valid = (deg - k0) < 64 ? (deg - k0) : 64;
        acc += accum_pairs(lreg, valid, h, cl);
    }
    return acc / (sum + 1e-16f);
}

// ---------------- K2: fused gather, XCD-pinned by batch (b = blockIdx & 7) ----------------
__global__ __launch_bounds__(256) void k2_gather(
        const int* __restrict__ bcnt, const int2* __restrict__ bbuck,
        const int* __restrict__ scnt, const int2* __restrict__ sbuck,
        const unsigned short* __restrict__ h_b, const unsigned short* __restrict__ h_s,
        const float* __restrict__ asb, const float* __restrict__ adb,
        const float* __restrict__ ass, const float* __restrict__ ads,
        const float* __restrict__ elog_b, const float* __restrict__ elog_s,
        const float* __restrict__ bias_b, const float* __restrict__ bias_s,
        const float* __restrict__ P, float* __restrict__ out) {
    __shared__ float4 ldsq[4][2][32];   // per-wave: 32 float4 = 64 (p,src) pairs per graph
    int blk = blockIdx.x;
    int b = blk & 7;                               // XCD pin: round-robin blk->XCD
    int w = threadIdx.x >> 6;
    int g = ((blk >> 3) << 2) + w;
    int lane = threadIdx.x & 63;
    int cl = lane < CC ? lane : CC - 1;
    float4* lregb = &ldsq[w][0][0];
    float4* lregs = &ldsq[w][1][0];

    int degb = bcnt[g];  degb = degb < BCAP ? degb : BCAP;
    int sct = g >> 9;            // NN = 2^9
    int n = g & (NN - 1);
    int degs = scnt[n];  degs = degs < SCAP ? degs : SCAP;

    const int2* bb = bbuck + (size_t)g * BCAP;
    const int2* sb = sbuck + (size_t)n * SCAP;
    const float* asrcb = asb + (size_t)b * NG;
    const float* elb   = elog_b + (size_t)b * EBN;
    const unsigned short* hb = h_b + (size_t)b * NG * CC;
    size_t basebg = (size_t)b * NG + (size_t)sct * NN;
    const float* asrcs = ass + basebg;
    const float* els   = elog_s + (size_t)b * ESN;
    const unsigned short* hs = h_s + basebg * CC;
    float adgb = adb[(size_t)b * NG + g];
    float adgs = ads[basebg + n];

    float vb, vs;
    if (degb <= 64 && degs <= 64) {
        bool vB = lane < degb, vS = lane < degs;
        int2 seb = bb[vB ? lane : 0];
        int2 ses = sb[vS ? lane : 0];
        float lgb = asrcb[seb.x] + adgb + elb[seb.y];
        float lgs = asrcs[ses.x] + adgs + els[ses.y];
        lgb = lgb >= 0.f ? lgb : 0.2f * lgb;
        lgs = lgs >= 0.f ? lgs : 0.2f * lgs;
        float pb = vB ? __expf(lgb) : 0.f;   // logits bounded (~|5|): no max needed
        float ps = vS ? __expf(lgs) : 0.f;
        ((float2*)lregb)[lane] = make_float2(pb, __int_as_float(seb.x));
        ((float2*)lregs)[lane] = make_float2(ps, __int_as_float(ses.x));
        float sumb = wave_sum(pb);
        float sums = wave_sum(ps);
        asm volatile("s_waitcnt lgkmcnt(0)" ::: "memory");
        float accb = accum_pairs(lregb, degb, hb, cl);
        float accs = accum_pairs(lregs, degs, hs, cl);
        vb = degb > 0 ? accb / (sumb + 1e-16f) : 0.f;
        vs = degs > 0 ? accs / (sums + 1e-16f) : 0.f;
    } else {
        vb = gat_big(bb, degb, asrcb, elb, hb, adgb, lane, cl, lregb);
        vs = gat_big(sb, degs, asrcs, els, hs, adgs, lane, cl, lregs);
    }

    if (lane < CC) {
        float ob = vb + bias_b[lane];
        ob = ob >= 0.f ? ob : 0.01f * ob;
        float os = vs + bias_s[lane];
        out[((size_t)b * NG + g) * CC + lane] = P[10] * ob + P[11] * os;
    }
}

extern "C" void kernel_launch(void* const* d_in, const int* in_sizes, int n_in,
                              void* d_out, int out_size, void* d_ws, size_t ws_size,
                              hipStream_t stream) {
    const float* x          = (const float*)d_in[0];
    const int*   bend_ei    = (const int*)d_in[1];
    const int*   sec_ei     = (const int*)d_in[2];
    const float* bend_attr  = (const float*)d_in[3];
    const float* sec_attr   = (const float*)d_in[4];
    const float* enc_W      = (const float*)d_in[5];
    const float* enc_b      = (const float*)d_in[6];
    const float* Wb         = (const float*)d_in[7];
    const float* a_src_b    = (const float*)d_in[8];
    const float* a_dst_b    = (const float*)d_in[9];
    const float* We_b       = (const float*)d_in[10];
    const float* a_e_b      = (const float*)d_in[11];
    const float* bias_b     = (const float*)d_in[12];
    const float* Ws         = (const float*)d_in[13];
    const float* a_src_s    = (const float*)d_in[14];
    const float* a_dst_s    = (const float*)d_in[15];
    const float* We_s       = (const float*)d_in[16];
    const float* a_e_s      = (const float*)d_in[17];
    const float* bias_s     = (const float*)d_in[18];
    const float* mix_w      = (const float*)d_in[19];
    float* out = (float*)d_out;

    char* base = (char*)d_ws;
    size_t off = 0;
    auto alloc = [&](size_t bytes) -> char* {
        off = (off + 255) & ~(size_t)255;
        char* p = base + off;
        off += bytes;
        return p;
    };
    float* P       = (float*)alloc(128 * sizeof(float));
    int* bcnt      = (int*)alloc(NG * sizeof(int));
    int* scnt      = (int*)alloc(NN * sizeof(int));
    int2* bbuck    = (int2*)alloc((size_t)NG * BCAP * sizeof(int2));
    int2* sbuck    = (int2*)alloc((size_t)NN * SCAP * sizeof(int2));
    unsigned short* h_b = (unsigned short*)alloc((size_t)BB * NG * CC * sizeof(unsigned short));
    unsigned short* h_s = (unsigned short*)alloc((size_t)BB * NG * CC * sizeof(unsigned short));
    float* asb     = (float*)alloc((size_t)BB * NG * sizeof(float));
    float* adb     = (float*)alloc((size_t)BB * NG * sizeof(float));
    float* ass     = (float*)alloc((size_t)BB * NG * sizeof(float));
    float* ads     = (float*)alloc((size_t)BB * NG * sizeof(float));
    float* elog_b  = (float*)alloc((size_t)BB * EBN * sizeof(float));
    float* elog_s  = (float*)alloc((size_t)BB * ESN * sizeof(float));
    (void)ws_size; (void)in_sizes; (void)n_in; (void)out_size;

    k0_init<<<(NG + 255) / 256, 256, 0, stream>>>(enc_W, enc_b,
                                                  Wb, a_src_b, a_dst_b, We_b, a_e_b,
                                                  Ws, a_src_s, a_dst_s, We_s, a_e_s,
                                                  mix_w, P, bcnt, scnt);

    int k1_blocks = FEAT_NB + FILLB_NB + FILLS_NB + ELOG_NB;
    k1_build<<<k1_blocks, 256, 0, stream>>>(x, bend_ei, sec_ei, bend_attr, sec_attr,
                                            Wb, Ws, P, h_b, h_s, asb, adb, ass, ads,
                                            elog_b, elog_s, bcnt, bbuck, scnt, sbuck);

    int k2_blocks = 8 * (NG / 4);   // b = blk & 7, 4 nodes per block
    k2_gather<<<k2_blocks, 256, 0, stream>>>(bcnt, bbuck, scnt, sbuck, h_b, h_s,
                                             asb, adb, ass, ads, elog_b, elog_s,
                                             bias_b, bias_s, P, out);
}

// Round 5
// 181.769 us; speedup vs baseline: 1.4759x; 1.4759x over previous
//
#include <hip/hip_runtime.h>
#include <math.h>

// Problem dims
#define BB 8
#define SS 32
#define NN 512
#define FIN 24
#define CC 56
#define EBN 262144
#define ESN 8192
#define EDD 4
#define NG (SS*NN)   // 16384 nodes per sample in bend graph
#define BCAP 128     // bucket capacity (avg deg 16, Poisson-tail max ~45)
#define SCAP 128
#define HROW (CC*2)  // h row bytes (bf16)

// ---------------- small helpers ----------------
__device__ __forceinline__ float bf2f(unsigned short u) {
    union { unsigned int i; float f; } w; w.i = ((unsigned int)u) << 16; return w.f;
}
__device__ __forceinline__ unsigned short f2bf(float f) {
    union { float f; unsigned int i; } w; w.f = f;
    unsigned int r = (w.i + 0x7FFFu + ((w.i >> 16) & 1u)) >> 16;
    return (unsigned short)r;
}
__device__ __forceinline__ float wave_sum(float v) {
    #pragma unroll
    for (int o = 32; o > 0; o >>= 1) v += __shfl_xor(v, o);
    return v;
}

// ---------------- K0: prep params + zero bucket counts ----------------
// P layout: [0..3]=u_bend, [4]=c_bend, [5..8]=u_sec, [9]=c_sec, [10]=w0, [11]=w1
//           [16..39]=wa_src_b, [40..63]=wa_dst_b, [64..87]=wa_src_s, [88..111]=wa_dst_s
__global__ void k0_init(const float* enc_W, const float* enc_b,
                        const float* Wb, const float* a_src_b, const float* a_dst_b,
                        const float* We_b, const float* a_e_b,
                        const float* Ws, const float* a_src_s, const float* a_dst_s,
                        const float* We_s, const float* a_e_s,
                        const float* mix_w, float* P,
                        int* bcnt, int* scnt) {
    int i = blockIdx.x * blockDim.x + threadIdx.x;
    if (i < NG) bcnt[i] = 0;
    if (i < NN) scnt[i] = 0;
    if (i < 96) {
        // fold W @ a vectors: P[16 + v*24 + f] = sum_c W[f][c] * a[c]
        int v = i / FIN, f = i % FIN;
        const float* W = (v < 2) ? Wb : Ws;
        const float* a = (v == 0) ? a_src_b : (v == 1) ? a_dst_b : (v == 2) ? a_src_s : a_dst_s;
        float d = 0.f;
        for (int c = 0; c < CC; ++c) d = fmaf(W[f*CC + c], a[c], d);
        P[16 + i] = d;
    }
    if (i == 0) {
        float tb[EDD], ts[EDD];
        for (int j = 0; j < EDD; ++j) {
            float vb = 0.f, vs = 0.f;
            for (int c = 0; c < CC; ++c) {
                vb += We_b[j*CC + c] * a_e_b[c];
                vs += We_s[j*CC + c] * a_e_s[c];
            }
            tb[j] = vb; ts[j] = vs;
        }
        float cb = 0.f, cs = 0.f;
        for (int j = 0; j < EDD; ++j) { cb += enc_b[j]*tb[j]; cs += enc_b[j]*ts[j]; }
        for (int d = 0; d < EDD; ++d) {
            float ub = 0.f, us = 0.f;
            for (int j = 0; j < EDD; ++j) {
                ub += enc_W[d*EDD + j] * tb[j];
                us += enc_W[d*EDD + j] * ts[j];
            }
            P[d] = ub; P[5 + d] = us;
        }
        P[4] = cb; P[9] = cs;
        float m0 = mix_w[0], m1 = mix_w[1];
        float mm = fmaxf(m0, m1);
        float e0 = expf(m0 - mm), e1 = expf(m1 - mm);
        float inv = 1.f / (e0 + e1);
        P[10] = e0 * inv; P[11] = e1 * inv;
    }
}

// ---------------- K1: node features + bucket fill + edge logits (grid-partitioned)
#define FEAT_NB (BB*NG/16)             // 8192 blocks: 4 waves x 4 nodes = 16 nodes/block
#define FILLB_NB ((EBN+255)/256)       // 1024
#define FILLS_NB ((ESN+255)/256)       // 32
#define ELOG_NB ((BB*(EBN+ESN)+255)/256) // 8448

__global__ __launch_bounds__(256, 4) void k1_build(
        const float* __restrict__ x,
        const int* __restrict__ bend_ei, const int* __restrict__ sec_ei,
        const float* __restrict__ bend_attr, const float* __restrict__ sec_attr,
        const float* __restrict__ Wb, const float* __restrict__ Ws,
        const float* __restrict__ P,
        unsigned short* __restrict__ h_b, unsigned short* __restrict__ h_s,
        float* __restrict__ asb, float* __restrict__ adb,
        float* __restrict__ ass, float* __restrict__ ads,
        float* __restrict__ elog_b, float* __restrict__ elog_s,
        int* __restrict__ bcnt, int2* __restrict__ bbuck,
        int* __restrict__ scnt, int2* __restrict__ sbuck) {
    int blk = blockIdx.x;
    if (blk < FEAT_NB) {
        // ---- node features, 4 nodes per wave; W columns register-resident.
        // pseudo-channels: lane 56 -> alpha_src, lane 57 -> alpha_dst (folded W@a)
        int w = threadIdx.x >> 6;
        int lane = threadIdx.x & 63;
        int node0 = (blk << 4) + (w << 2);
        float wcb[FIN], wcs[FIN];
        #pragma unroll
        for (int f = 0; f < FIN; ++f) {
            float vb = 0.f, vs = 0.f;
            if (lane < CC) {
                vb = Wb[f*CC + lane];
                vs = Ws[f*CC + lane];
            } else if (lane < 58) {
                vb = P[16 + (lane - 56) * FIN + f];
                vs = P[16 + (lane - 54) * FIN + f];   // (2 + lane-56)*24
            }
            wcb[f] = vb; wcs[f] = vs;
        }
        #pragma unroll 1
        for (int n0 = 0; n0 < 4; ++n0) {
            size_t node = (size_t)node0 + n0;
            const float4* x4 = (const float4*)(x + node * FIN);
            float xv[FIN];
            #pragma unroll
            for (int q = 0; q < FIN/4; ++q) {
                float4 v = x4[q];
                xv[4*q+0] = v.x; xv[4*q+1] = v.y; xv[4*q+2] = v.z; xv[4*q+3] = v.w;
            }
            float hb = 0.f, hs = 0.f;
            #pragma unroll
            for (int f = 0; f < FIN; ++f) {
                hb = fmaf(xv[f], wcb[f], hb);
                hs = fmaf(xv[f], wcs[f], hs);
            }
            if (lane < CC) {
                h_b[node*CC + lane] = f2bf(hb);
                h_s[node*CC + lane] = f2bf(hs);
            } else if (lane == 56) {
                asb[node] = hb; ass[node] = hs;
            } else if (lane == 57) {
                adb[node] = hb; ads[node] = hs;
            }
        }
    } else if (blk < FEAT_NB + FILLB_NB) {
        // ---- bend bucket fill
        int i = (blk - FEAT_NB) * 256 + threadIdx.x;
        if (i < EBN) {
            int d = bend_ei[EBN + i];
            int p = atomicAdd(&bcnt[d], 1);
            if (p < BCAP) bbuck[(size_t)d * BCAP + p] = make_int2(bend_ei[i], i);
        }
    } else if (blk < FEAT_NB + FILLB_NB + FILLS_NB) {
        // ---- section bucket fill
        int i = (blk - FEAT_NB - FILLB_NB) * 256 + threadIdx.x;
        if (i < ESN) {
            int d = sec_ei[ESN + i];
            int p = atomicAdd(&scnt[d], 1);
            if (p < SCAP) sbuck[(size_t)d * SCAP + p] = make_int2(sec_ei[i], i);
        }
    } else {
        // ---- per-edge scalar logit terms
        int i = (blk - FEAT_NB - FILLB_NB - FILLS_NB) * 256 + threadIdx.x;
        const int nb = BB * EBN;
        if (i < nb) {
            float4 a = ((const float4*)bend_attr)[i];
            elog_b[i] = a.x*P[0] + a.y*P[1] + a.z*P[2] + a.w*P[3] + P[4];
        } else if (i < nb + BB * ESN) {
            int j = i - nb;
            float4 a = ((const float4*)sec_attr)[j];
            elog_s[j] = a.x*P[5] + a.y*P[6] + a.z*P[7] + a.w*P[8] + P[9];
        }
    }
}

// ---------------- accumulation over LDS-packed (p, byte-offset) pairs ----------------
// lreg holds pairs: float4 = {p0, off0_bits, p1, off1_bits}; offsets are
// prescaled src*HROW byte offsets. Same-address LDS reads broadcast.
__device__ __forceinline__ float accum_pairs(const float4* __restrict__ lreg, int deg,
                                             const char* __restrict__ hB, int cl2) {
    float acc = 0.f;
    int degQ = (deg + 1) >> 1;
    int j = 0;
    for (; j + 4 <= degQ; j += 4) {     // 8 edges per iter
        float4 q0 = lreg[j], q1 = lreg[j+1], q2 = lreg[j+2], q3 = lreg[j+3];
        float v0 = bf2f(*(const unsigned short*)(hB + (__float_as_int(q0.y) + cl2)));
        float v1 = bf2f(*(const unsigned short*)(hB + (__float_as_int(q0.w) + cl2)));
        float v2 = bf2f(*(const unsigned short*)(hB + (__float_as_int(q1.y) + cl2)));
        float v3 = bf2f(*(const unsigned short*)(hB + (__float_as_int(q1.w) + cl2)));
        float v4 = bf2f(*(const unsigned short*)(hB + (__float_as_int(q2.y) + cl2)));
        float v5 = bf2f(*(const unsigned short*)(hB + (__float_as_int(q2.w) + cl2)));
        float v6 = bf2f(*(const unsigned short*)(hB + (__float_as_int(q3.y) + cl2)));
        float v7 = bf2f(*(const unsigned short*)(hB + (__float_as_int(q3.w) + cl2)));
        acc = fmaf(q0.x, v0, acc); acc = fmaf(q0.z, v1, acc);
        acc = fmaf(q1.x, v2, acc); acc = fmaf(q1.z, v3, acc);
        acc = fmaf(q2.x, v4, acc); acc = fmaf(q2.z, v5, acc);
        acc = fmaf(q3.x, v6, acc); acc = fmaf(q3.z, v7, acc);
    }
    for (; j < degQ; ++j) {
        float4 q = lreg[j];
        acc = fmaf(q.x, bf2f(*(const unsigned short*)(hB + (__float_as_int(q.y) + cl2))), acc);
        acc = fmaf(q.z, bf2f(*(const unsigned short*)(hB + (__float_as_int(q.w) + cl2))), acc);
    }
    return acc;
}

// rare fallback: degree > 64 (chunked, no-max softmax)
__device__ __noinline__ float gat_big(const int2* __restrict__ buck, int deg,
                                      const float* __restrict__ asrc,
                                      const float* __restrict__ el,
                                      const char* __restrict__ hB,
                                      float adg, int lane, int cl2, float4* lreg) {
    if (deg <= 0) return 0.f;
    float2* wp = (float2*)lreg;
    float acc = 0.f, sum = 0.f;
    for (int k0 = 0; k0 < deg; k0 += 64) {
        int k = k0 + lane;
        bool v = k < deg;
        int2 se = buck[v ? k : 0];
        float lg = asrc[se.x] + adg + el[se.y];
        lg = lg >= 0.f ? lg : 0.2f * lg;
        float p = v ? __expf(lg) : 0.f;
        asm volatile("s_waitcnt lgkmcnt(0)" ::: "memory");  // prior reads done before overwrite
        wp[lane] = make_float2(p, __int_as_float(se.x * HROW));
        sum += wave_sum(p);
        asm volatile("s_waitcnt lgkmcnt(0)" ::: "memory");
        int valid = (deg - k0) < 64 ? (deg - k0) : 64;
        acc += accum_pairs(lreg, valid, hB, cl2);
    }
    return acc / (sum + 1e-16f);
}

// ---------------- K2: fused gather, XCD-pinned by batch (b = blockIdx & 7) ----------------
__global__ __launch_bounds__(256, 8) void k2_gather(
        const int* __restrict__ bcnt, const int2* __restrict__ bbuck,
        const int* __restrict__ scnt, const int2* __restrict__ sbuck,
        const unsigned short* __restrict__ h_b, const unsigned short* __restrict__ h_s,
        const float* __restrict__ asb, const float* __restrict__ adb,
        const float* __restrict__ ass, const float* __restrict__ ads,
        const float* __restrict__ elog_b, const float* __restrict__ elog_s,
        const float* __restrict__ bias_b, const float* __restrict__ bias_s,
        const float* __restrict__ P, float* __restrict__ out) {
    __shared__ float4 ldsq[4][2][32];   // per-wave: 32 float4 = 64 (p,off) pairs per graph
    int blk = blockIdx.x;
    int b = blk & 7;                               // XCD pin: round-robin blk->XCD
    int w = threadIdx.x >> 6;
    int g = ((blk >> 3) << 2) + w;
    int lane = threadIdx.x & 63;
    int cl2 = (lane < CC ? lane : 0) * 2;
    float4* lregb = &ldsq[w][0][0];
    float4* lregs = &ldsq[w][1][0];

    int degb = bcnt[g];  degb = degb < BCAP ? degb : BCAP;
    int sct = g >> 9;            // NN = 2^9
    int n = g & (NN - 1);
    int degs = scnt[n];  degs = degs < SCAP ? degs : SCAP;

    const int2* bb = bbuck + (size_t)g * BCAP;
    const int2* sb = sbuck + (size_t)n * SCAP;
    const float* asrcb = asb + (size_t)b * NG;
    const float* elb   = elog_b + (size_t)b * EBN;
    const char* hbB = (const char*)(h_b + (size_t)b * NG * CC);
    size_t basebg = (size_t)b * NG + (size_t)sct * NN;
    const float* asrcs = ass + basebg;
    const float* els   = elog_s + (size_t)b * ESN;
    const char* hsB = (const char*)(h_s + basebg * CC);
    float adgb = adb[(size_t)b * NG + g];
    float adgs = ads[basebg + n];

    float vb, vs;
    if (degb <= 64 && degs <= 64) {
        bool vB = lane < degb, vS = lane < degs;
        int2 seb = bb[vB ? lane : 0];
        int2 ses = sb[vS ? lane : 0];
        float lgb = asrcb[seb.x] + adgb + elb[seb.y];
        float lgs = asrcs[ses.x] + adgs + els[ses.y];
        lgb = lgb >= 0.f ? lgb : 0.2f * lgb;
        lgs = lgs >= 0.f ? lgs : 0.2f * lgs;
        float pb = vB ? __expf(lgb) : 0.f;   // logits bounded (~|5|): no max needed
        float ps = vS ? __expf(lgs) : 0.f;
        ((float2*)lregb)[lane] = make_float2(pb, __int_as_float(seb.x * HROW));
        ((float2*)lregs)[lane] = make_float2(ps, __int_as_float(ses.x * HROW));
        float sumb = wave_sum(pb);
        float sums = wave_sum(ps);
        asm volatile("s_waitcnt lgkmcnt(0)" ::: "memory");
        float accb = accum_pairs(lregb, degb, hbB, cl2);
        float accs = accum_pairs(lregs, degs, hsB, cl2);
        vb = accb / (sumb + 1e-16f);
        vs = accs / (sums + 1e-16f);
    } else {
        vb = gat_big(bb, degb, asrcb, elb, hbB, adgb, lane, cl2, lregb);
        vs = gat_big(sb, degs, asrcs, els, hsB, adgs, lane, cl2, lregs);
    }

    if (lane < CC) {
        float ob = vb + bias_b[lane];
        ob = ob >= 0.f ? ob : 0.01f * ob;
        float os = vs + bias_s[lane];
        out[((size_t)b * NG + g) * CC + lane] = P[10] * ob + P[11] * os;
    }
}

extern "C" void kernel_launch(void* const* d_in, const int* in_sizes, int n_in,
                              void* d_out, int out_size, void* d_ws, size_t ws_size,
                              hipStream_t stream) {
    const float* x          = (const float*)d_in[0];
    const int*   bend_ei    = (const int*)d_in[1];
    const int*   sec_ei     = (const int*)d_in[2];
    const float* bend_attr  = (const float*)d_in[3];
    const float* sec_attr   = (const float*)d_in[4];
    const float* enc_W      = (const float*)d_in[5];
    const float* enc_b      = (const float*)d_in[6];
    const float* Wb         = (const float*)d_in[7];
    const float* a_src_b    = (const float*)d_in[8];
    const float* a_dst_b    = (const float*)d_in[9];
    const float* We_b       = (const float*)d_in[10];
    const float* a_e_b      = (const float*)d_in[11];
    const float* bias_b     = (const float*)d_in[12];
    const float* Ws         = (const float*)d_in[13];
    const float* a_src_s    = (const float*)d_in[14];
    const float* a_dst_s    = (const float*)d_in[15];
    const float* We_s       = (const float*)d_in[16];
    const float* a_e_s      = (const float*)d_in[17];
    const float* bias_s     = (const float*)d_in[18];
    const float* mix_w      = (const float*)d_in[19];
    float* out = (float*)d_out;

    char* base = (char*)d_ws;
    size_t off = 0;
    auto alloc = [&](size_t bytes) -> char* {
        off = (off + 255) & ~(size_t)255;
        char* p = base + off;
        off += bytes;
        return p;
    };
    float* P       = (float*)alloc(128 * sizeof(float));
    int* bcnt      = (int*)alloc(NG * sizeof(int));
    int* scnt      = (int*)alloc(NN * sizeof(int));
    int2* bbuck    = (int2*)alloc((size_t)NG * BCAP * sizeof(int2));
    int2* sbuck    = (int2*)alloc((size_t)NN * SCAP * sizeof(int2));
    unsigned short* h_b = (unsigned short*)alloc((size_t)BB * NG * CC * sizeof(unsigned short));
    unsigned short* h_s = (unsigned short*)alloc((size_t)BB * NG * CC * sizeof(unsigned short));
    float* asb     = (float*)alloc((size_t)BB * NG * sizeof(float));
    float* adb     = (float*)alloc((size_t)BB * NG * sizeof(float));
    float* ass     = (float*)alloc((size_t)BB * NG * sizeof(float));
    float* ads     = (float*)alloc((size_t)BB * NG * sizeof(float));
    float* elog_b  = (float*)alloc((size_t)BB * EBN * sizeof(float));
    float* elog_s  = (float*)alloc((size_t)BB * ESN * sizeof(float));
    (void)ws_size; (void)in_sizes; (void)n_in; (void)out_size;

    k0_init<<<(NG + 255) / 256, 256, 0, stream>>>(enc_W, enc_b,
                                                  Wb, a_src_b, a_dst_b, We_b, a_e_b,
                                                  Ws, a_src_s, a_dst_s, We_s, a_e_s,
                                                  mix_w, P, bcnt, scnt);

    int k1_blocks = FEAT_NB + FILLB_NB + FILLS_NB + ELOG_NB;
    k1_build<<<k1_blocks, 256, 0, stream>>>(x, bend_ei, sec_ei, bend_attr, sec_attr,
                                            Wb, Ws, P, h_b, h_s, asb, adb, ass, ads,
                                            elog_b, elog_s, bcnt, bbuck, scnt, sbuck);

    int k2_blocks = 8 * (NG / 4);   // b = blk & 7, 4 nodes per block
    k2_gather<<<k2_blocks, 256, 0, stream>>>(bcnt, bbuck, scnt, sbuck, h_b, h_s,
                                             asb, adb, ass, ads, elog_b, elog_s,
                                             bias_b, bias_s, P, out);
}